// Round 3
// baseline (787.589 us; speedup 1.0000x reference)
//
#include <hip/hip_runtime.h>

// L_CA1 plus-phase: net = a_ECin@W_ECin + a_CA3@W_CA3 + a_ECout@W_ECout  [8192 x 64]
// act = relu(net)/(relu(net)+1); kWTA top-6 per row; out = activity + 0.1*(sparse - activity)
//
// v3: lane=row, W wave-uniform via scalar loads (v_fmac v,s,v), and A staged
// through LDS with coalesced global_load_lds (width 16). v2's per-lane A loads
// were a 64-line scatter per instruction (row stride 16KB) -> TA-serialized,
// VALUBusy 31%. Staging reads 4 rows x 256B contiguous per instruction.
// LDS read (lane=row, row stride 256B) would be a 32-way bank conflict, so the
// global SOURCE chunk is XOR-pre-swizzled and the ds_read applies the same
// involution (linear LDS dest, rule: both-sides-or-neither).
// Numerics: exact same k-order + 4-way partial interleave + pairwise tree-sum
// as v2 (which matched numpy bitwise, absmax 0.0) — kWTA top-6 is
// discontinuous, so accumulation order is part of correctness.

typedef float f32x4 __attribute__((ext_vector_type(4)));

#define B_ROWS 8192
#define NCOL   64
#define KCHUNK 1024
#define NCHUNK 10        // 4 (ECin, K=4096) + 2 (CA3, K=2048) + 4 (ECout, K=4096)
#define TILE_K 64        // k-floats per LDS tile
#define NTILES (KCHUNK / TILE_K)   // 16

typedef const unsigned int __attribute__((address_space(1)))* gl_p;
typedef unsigned int __attribute__((address_space(3)))*       ld_p;

// ---------------- GEMM partial kernel ----------------
// block = 256 threads = 4 waves; lane = row (64 rows/block), wave = 16-col slice.
// Per tile: each wave issues 4 global_load_lds (its 16 rows), computes 16
// k-subtiles of 4k x 16cols from the previous tile's LDS buffer.

template<int KSEG>
__device__ __forceinline__ void gemm_chunk(const float* __restrict__ A,
                                           const float* __restrict__ W,
                                           float* __restrict__ P,
                                           int kof, int rb,
                                           float (*lds)[64 * TILE_K])
{
    const int tid  = threadIdx.x;
    const int lane = tid & 63;
    const int wv   = __builtin_amdgcn_readfirstlane(tid >> 6);
    const int c0   = wv * 16;            // wave-uniform column base
    const int subr = lane >> 4;          // 0..3   sub-row within a load slot
    const int cch  = lane & 15;          // 16B-chunk slot 0..15 within a row

    // Per-lane global source pointers for the 4 staging slots of this wave.
    // Slot q covers tile-rows r = 16*wv + 4*q + subr; source chunk is
    // XOR-swizzled: g = cch ^ (r & 15)  (r&15 == 4q + subr, wave-independent).
    const float* gsrc[4];
#pragma unroll
    for (int q = 0; q < 4; ++q) {
        const int r = 16 * wv + 4 * q + subr;          // row within tile
        const int g = cch ^ (4 * q + subr);            // swizzled source chunk
        gsrc[q] = A + (size_t)(rb * 64 + r) * KSEG + kof + g * 4;
    }

    float p0[16], p1[16], p2[16], p3[16];
#pragma unroll
    for (int j = 0; j < 16; ++j) { p0[j] = 0.f; p1[j] = 0.f; p2[j] = 0.f; p3[j] = 0.f; }

    // ---- prologue: stage tile 0 into buffer 0
#pragma unroll
    for (int q = 0; q < 4; ++q)
        __builtin_amdgcn_global_load_lds((gl_p)(const void*)gsrc[q],
                                         (ld_p)(void*)&lds[0][(16 * wv + 4 * q) * TILE_K],
                                         16, 0, 0);
    __syncthreads();   // drains vmcnt(0) per-wave, then barrier

    for (int i = 0; i < NTILES; ++i) {
        const int cur = i & 1;

        // stage tile i+1 into the other buffer (completes under compute;
        // that buffer's readers all finished before the last barrier)
        if (i + 1 < NTILES) {
#pragma unroll
            for (int q = 0; q < 4; ++q)
                __builtin_amdgcn_global_load_lds(
                    (gl_p)(const void*)(gsrc[q] + (size_t)(i + 1) * TILE_K),
                    (ld_p)(void*)&lds[cur ^ 1][(16 * wv + 4 * q) * TILE_K],
                    16, 0, 0);
        }

        // compute tile i: 16 k-subtiles of 4 k each
        const float* __restrict__ wbase = W + (size_t)(kof + i * TILE_K) * NCOL + c0;
#pragma unroll
        for (int t = 0; t < 16; ++t) {
            // swizzled read: lds[lane][chunk t] lives at chunk index t ^ (lane&15)
            const f32x4 av = *(const f32x4*)&lds[cur][lane * TILE_K + ((t ^ cch) * 4)];
            const float* __restrict__ wt = wbase + (size_t)4 * t * NCOL;  // wave-uniform -> s_load
#pragma unroll
            for (int j = 0; j < 16; ++j) p0[j] = fmaf(av.x, wt[j],            p0[j]);
#pragma unroll
            for (int j = 0; j < 16; ++j) p1[j] = fmaf(av.y, wt[NCOL + j],     p1[j]);
#pragma unroll
            for (int j = 0; j < 16; ++j) p2[j] = fmaf(av.z, wt[2 * NCOL + j], p2[j]);
#pragma unroll
            for (int j = 0; j < 16; ++j) p3[j] = fmaf(av.w, wt[3 * NCOL + j], p3[j]);
        }
        __syncthreads();   // all reads of buf[cur] done; buf[cur^1] fully landed
    }

    // pairwise tree-sum, per-lane store of 16 consecutive floats (dwordx4 x4)
    float* __restrict__ dst = P + (size_t)(rb * 64 + lane) * NCOL + c0;
#pragma unroll
    for (int j = 0; j < 16; ++j)
        dst[j] = (p0[j] + p1[j]) + (p2[j] + p3[j]);
}

__global__ __launch_bounds__(256, 5)
void gemm_kernel(const float* __restrict__ a_ECin,  const float* __restrict__ a_CA3,
                 const float* __restrict__ a_ECout, const float* __restrict__ W_ECin,
                 const float* __restrict__ W_CA3,   const float* __restrict__ W_ECout,
                 float* __restrict__ ws)
{
    __shared__ float lds[2][64 * TILE_K];   // 2 x 16 KB, shared by all chunk paths

    const int bid   = blockIdx.x;
    const int chunk = bid >> 7;    // 0..9
    const int rb    = bid & 127;   // row-block of 64
    float* P = ws + (size_t)chunk * (B_ROWS * NCOL);

    if (chunk < 4)      gemm_chunk<4096>(a_ECin,  W_ECin,  P, chunk * KCHUNK, rb, lds);
    else if (chunk < 6) gemm_chunk<2048>(a_CA3,   W_CA3,   P, (chunk - 4) * KCHUNK, rb, lds);
    else                gemm_chunk<4096>(a_ECout, W_ECout, P, (chunk - 6) * KCHUNK, rb, lds);
}

// ---------------- epilogue: reduce partials + nxx1 + kWTA(6) + Euler ----------------
// (unchanged from v2 — passed with absmax 0.0)

__global__ __launch_bounds__(256)
void epilogue_kernel(const float* __restrict__ ws,
                     const float* __restrict__ activity,
                     float* __restrict__ out)
{
    const int lane = threadIdx.x & 63;
    const int wv   = threadIdx.x >> 6;
    const int row0 = blockIdx.x * 16 + wv * 4;

#pragma unroll
    for (int rr = 0; rr < 4; ++rr) {
        const int row = row0 + rr;
        const size_t off = (size_t)row * NCOL + lane;

        float c[NCHUNK];
#pragma unroll
        for (int i = 0; i < NCHUNK; ++i)
            c[i] = ws[(size_t)i * (B_ROWS * NCOL) + off];
        const float t0 = c[0] + c[1], t1 = c[2] + c[3], t2 = c[4] + c[5],
                    t3 = c[6] + c[7], t4 = c[8] + c[9];
        const float net = ((t0 + t1) + (t2 + t3)) + t4;

        const float pos = fmaxf(net, 0.0f);
        const float act = pos / (pos + 1.0f);

        // 6th-largest of 64, duplicate-safe (mask exactly one lane per extraction)
        float v = act, thr = 0.0f;
#pragma unroll
        for (int i = 0; i < 6; ++i) {
            float m = v;
#pragma unroll
            for (int off2 = 32; off2 >= 1; off2 >>= 1)
                m = fmaxf(m, __shfl_xor(m, off2, 64));
            const unsigned long long b = __ballot(v == m);
            const int first = __ffsll(b) - 1;
            if (lane == first) v = -__builtin_inff();
            thr = m;
        }

        const float sp = (act >= thr) ? act : 0.0f;
        const float a0 = activity[off];
        out[off] = fmaf(0.1f, sp - a0, a0);
    }
}

// ---------------- launcher ----------------
extern "C" void kernel_launch(void* const* d_in, const int* in_sizes, int n_in,
                              void* d_out, int out_size, void* d_ws, size_t ws_size,
                              hipStream_t stream)
{
    (void)in_sizes; (void)n_in; (void)out_size; (void)ws_size;
    const float* a_ECin   = (const float*)d_in[0];
    const float* a_CA3    = (const float*)d_in[1];
    const float* a_ECout  = (const float*)d_in[2];
    const float* W_ECin   = (const float*)d_in[3];
    const float* W_CA3    = (const float*)d_in[4];
    const float* W_ECout  = (const float*)d_in[5];
    const float* activity = (const float*)d_in[6];
    float* out = (float*)d_out;
    float* ws  = (float*)d_ws;   // 10 * 8192 * 64 * 4 = 20 MB

    hipLaunchKernelGGL(gemm_kernel, dim3(NCHUNK * 128), dim3(256), 0, stream,
                       a_ECin, a_CA3, a_ECout, W_ECin, W_CA3, W_ECout, ws);
    hipLaunchKernelGGL(epilogue_kernel, dim3(B_ROWS / 16), dim3(256), 0, stream,
                       ws, activity, out);
}